// Round 3
// baseline (286.767 us; speedup 1.0000x reference)
//
#include <hip/hip_runtime.h>
#include <hip/hip_bf16.h>

typedef __attribute__((ext_vector_type(8))) short short8;
typedef __attribute__((ext_vector_type(4))) float floatx4;

#define M_DIM 8192
#define N_DIM 4096
#define K_DIM 4096
#define N_EXC 3277

typedef unsigned int u32;
typedef __attribute__((address_space(1))) const u32 gu32;
typedef __attribute__((address_space(3))) u32 lu32;

__device__ __forceinline__ void gload_lds16(const void* g, void* l) {
    __builtin_amdgcn_global_load_lds((gu32*)g, (lu32*)l, 16, 0, 0);
}

__device__ __forceinline__ unsigned short f2bf(float f) {
    u32 u = __builtin_bit_cast(u32, f);
    u32 lsb = (u >> 16) & 1u;
    u += 0x7fffu + lsb;
    return (unsigned short)(u >> 16);
}

// ---------------------------------------------------------------------------
// flag: 0 = int32, 1 = bool/u8, 2 = float32
__global__ void detect_kind(const unsigned char* __restrict__ w, int* __restrict__ flag) {
    __shared__ int sF, sO;
    const int tid = threadIdx.x;
    if (tid == 0) { sF = 0; sO = 0; }
    __syncthreads();
    int sawF = 0, sawO = 0;
    const unsigned char* p = w + tid * 16;
    #pragma unroll
    for (int i = 0; i < 16; ++i) {
        unsigned char b = p[i];
        int off = (tid * 16 + i) & 3;
        if (b == 0x3F && off == 3) sawF = 1;
        if (b != 0 && off != 0)    sawO = 1;
    }
    if (sawF) atomicOr(&sF, 1);
    if (sawO) atomicOr(&sO, 1);
    __syncthreads();
    if (tid == 0) *flag = sF ? 2 : (sO ? 1 : 0);
}

// ---------------------------------------------------------------------------
__global__ void conv_x_kernel(const float* __restrict__ x, unsigned short* __restrict__ xb) {
    size_t base = ((size_t)blockIdx.x * 256 + threadIdx.x) * 8;
    int k = (int)(base & (K_DIM - 1));
    floatx4 v0 = *(const floatx4*)(x + base);
    floatx4 v1 = *(const floatx4*)(x + base + 4);
    float f[8];
    f[0] = v0[0]; f[1] = v0[1]; f[2] = v0[2]; f[3] = v0[3];
    f[4] = v1[0]; f[5] = v1[1]; f[6] = v1[2]; f[7] = v1[3];
    short8 o;
    #pragma unroll
    for (int j = 0; j < 8; ++j) {
        float val = (k + j < N_EXC) ? f[j] : -4.0f * f[j];
        o[j] = (short)f2bf(val);
    }
    *(short8*)(xb + base) = o;
}

// ---------------------------------------------------------------------------
__global__ void conv_w_kernel(const void* __restrict__ w, const int* __restrict__ flag,
                              unsigned short* __restrict__ wbt) {
    __shared__ unsigned short t[64][65];
    const int kind = *flag;
    const int tid = threadIdx.x;
    const int bx = blockIdx.x & 63;
    const int by = blockIdx.x >> 6;
    const int k0 = by * 64, n0 = bx * 64;
    #pragma unroll
    for (int i = 0; i < 16; ++i) {
        int lin = i * 256 + tid;
        int r = lin >> 6, c = lin & 63;
        size_t gi = (size_t)(k0 + r) * N_DIM + (n0 + c);
        float val;
        if (kind == 0)      val = (float)((const int*)w)[gi];
        else if (kind == 1) val = (float)((const unsigned char*)w)[gi];
        else                val = ((const float*)w)[gi];
        t[r][c] = f2bf(val);
    }
    __syncthreads();
    #pragma unroll
    for (int i = 0; i < 16; ++i) {
        int lin = i * 256 + tid;
        int rr = lin >> 6, cc = lin & 63;
        wbt[(size_t)(n0 + rr) * K_DIM + (k0 + cc)] = t[cc][rr];
    }
}

// ---------------------------------------------------------------------------
// 256x256 tile, BK=64, 8 waves (2x4), 4x1 row-quarter phases, B-frag hold,
// cross-phase ar prefetch with counted lgkmcnt, vmcnt(4) ledger.
__global__ __launch_bounds__(512, 2)
void gemm8_kernel(const unsigned short* __restrict__ A,
                  const unsigned short* __restrict__ Bt,
                  float* __restrict__ C,
                  const float* __restrict__ scale_p) {
    __shared__ __align__(16) char lds[131072];

    const int tid  = threadIdx.x;
    const int wid  = tid >> 6;
    const int lane = tid & 63;
    const int l15  = lane & 15;
    const int l4   = lane >> 4;
    const int wr   = wid >> 2;      // 0..1  (128-row half)
    const int wc   = wid & 3;       // 0..3  (64-col quarter)

    int wg = blockIdx.x;
    wg = (wg & 7) * 64 + (wg >> 3);
    const int bm = wg >> 4;
    const int bn = wg & 15;

    const size_t a_base = (size_t)bm * 256 * K_DIM;
    const size_t b_base = (size_t)bn * 256 * K_DIM;

    const int u0   = wid * 2;
    const int lrow = lane >> 3;
    const int lswz = ((lane & 7) ^ lrow) << 3;
    const int xm   = (l15 & 7) << 4;

#define STAGEA(BUF, TILE, HALF) do { \
    _Pragma("unroll") \
    for (int j_ = 0; j_ < 2; ++j_) { \
        int u_ = u0 + j_; \
        int r0_ = (HALF)*64 + ((u_ & 8) << 4) + ((u_ & 7) << 3); \
        const unsigned short* g_ = A + a_base + (size_t)(r0_ + lrow) * K_DIM + (TILE)*64 + lswz; \
        gload_lds16(g_, lds + (BUF)*65536 + r0_*128); \
    } } while (0)

#define STAGEB(BUF, TILE, HALF) do { \
    _Pragma("unroll") \
    for (int j_ = 0; j_ < 2; ++j_) { \
        int u_ = u0 + j_; \
        int r0_ = (HALF)*32 + ((u_ >> 2) << 6) + ((u_ & 3) << 3); \
        const unsigned short* g_ = Bt + b_base + (size_t)(r0_ + lrow) * K_DIM + (TILE)*64 + lswz; \
        gload_lds16(g_, lds + (BUF)*65536 + 32768 + r0_*128); \
    } } while (0)

// read one A row-quarter (4 x ds_read_b128) into bank
#define RD_Q(BUF, Q, BANK) do { \
    _Pragma("unroll") \
    for (int mi_ = 0; mi_ < 2; ++mi_) { \
        _Pragma("unroll") \
        for (int kk_ = 0; kk_ < 2; ++kk_) \
            BANK[mi_][kk_] = *(const short8*)(lds + (BUF)*65536 \
                + (wr*128 + (Q)*32 + mi_*16 + l15)*128 + (((kk_<<6)|(l4<<4)) ^ xm)); \
    } } while (0)

// read one B 16-col group (2 x ds_read_b128)
#define RD_B(BUF, NI) do { \
    _Pragma("unroll") \
    for (int kk_ = 0; kk_ < 2; ++kk_) \
        br[NI][kk_] = *(const short8*)(lds + (BUF)*65536 + 32768 \
            + (wc*64 + (NI)*16 + l15)*128 + (((kk_<<6)|(l4<<4)) ^ xm)); \
    } while (0)

// 4 MFMAs: quarter Q x col-group NI
#define MF4(Q, NI, BANK) do { \
    _Pragma("unroll") \
    for (int mi_ = 0; mi_ < 2; ++mi_) { \
        _Pragma("unroll") \
        for (int kk_ = 0; kk_ < 2; ++kk_) \
            acc[(Q)*2+mi_][NI] = __builtin_amdgcn_mfma_f32_16x16x32_bf16( \
                BANK[mi_][kk_], br[NI][kk_], acc[(Q)*2+mi_][NI], 0, 0, 0); \
    } } while (0)

#define BAR()   __builtin_amdgcn_s_barrier()
#define SB()    __builtin_amdgcn_sched_barrier(0)
#define LG(N)   do { asm volatile("s_waitcnt lgkmcnt(" #N ")" ::: "memory"); SB(); } while (0)
#define VM4()   asm volatile("s_waitcnt vmcnt(4)" ::: "memory")
#define PRIO1() __builtin_amdgcn_s_setprio(1)
#define PRIO0() __builtin_amdgcn_s_setprio(0)

    short8 arA[2][2], arB[2][2], br[4][2];
    floatx4 acc[8][4] = {};

    // prologue: T0 full -> buf0 (oldest 8), T1 B -> buf1 (newest 4)
    STAGEB(0, 0, 0); STAGEB(0, 0, 1);
    STAGEA(0, 0, 0); STAGEA(0, 0, 1);
    STAGEB(1, 1, 0); STAGEB(1, 1, 1);
    VM4();                     // T0 landed; leaves T1-B(4)
    BAR();
    RD_Q(0, 0, arA); SB();     // prefetch q0 of tile0 (lgkm outstanding = 4)

    for (int i = 0; i < 32; ++i) {
        const int tb1 = (2*i + 1) & 63;
        const int tb2 = (2*i + 2) & 63;
        const int tb3 = (2*i + 3) & 63;

        // ---- tile 2i in buf0 ----
        // ph1: q0 prefetched; read all B + prefetch q1
        RD_B(0,0); SB(); RD_B(0,1); SB(); RD_B(0,2); SB(); RD_B(0,3); SB();
        RD_Q(0, 1, arB); SB();
        STAGEA(1, tb1, 0);
        BAR();
        PRIO1();
        LG(10); MF4(0,0,arA);
        LG(8);  MF4(0,1,arA);
        LG(6);  MF4(0,2,arA);
        LG(4);  MF4(0,3,arA);
        PRIO0();
        BAR();
        // ph2
        RD_Q(0, 2, arA); SB();
        STAGEA(1, tb1, 1); STAGEB(0, tb2, 0);
        BAR();
        PRIO1(); LG(4); MF4(1,0,arB); MF4(1,1,arB); MF4(1,2,arB); MF4(1,3,arB); PRIO0();
        BAR();
        // ph3
        RD_Q(0, 3, arB); SB();
        STAGEB(0, tb2, 1);
        BAR();
        PRIO1(); LG(4); MF4(2,0,arA); MF4(2,1,arA); MF4(2,2,arA); MF4(2,3,arA); PRIO0();
        BAR();
        // ph4: T+1 fully landed after VM4+BAR; prefetch next tile's q0 from buf1
        VM4();
        BAR();
        RD_Q(1, 0, arA); SB();
        PRIO1(); LG(4); MF4(3,0,arB); MF4(3,1,arB); MF4(3,2,arB); MF4(3,3,arB); PRIO0();
        BAR();

        // ---- tile 2i+1 in buf1 ----
        // ph5
        RD_B(1,0); SB(); RD_B(1,1); SB(); RD_B(1,2); SB(); RD_B(1,3); SB();
        RD_Q(1, 1, arB); SB();
        STAGEA(0, tb2, 0);
        BAR();
        PRIO1();
        LG(10); MF4(0,0,arA);
        LG(8);  MF4(0,1,arA);
        LG(6);  MF4(0,2,arA);
        LG(4);  MF4(0,3,arA);
        PRIO0();
        BAR();
        // ph6
        RD_Q(1, 2, arA); SB();
        STAGEA(0, tb2, 1); STAGEB(1, tb3, 0);
        BAR();
        PRIO1(); LG(4); MF4(1,0,arB); MF4(1,1,arB); MF4(1,2,arB); MF4(1,3,arB); PRIO0();
        BAR();
        // ph7
        RD_Q(1, 3, arB); SB();
        STAGEB(1, tb3, 1);
        BAR();
        PRIO1(); LG(4); MF4(2,0,arA); MF4(2,1,arA); MF4(2,2,arA); MF4(2,3,arA); PRIO0();
        BAR();
        // ph8
        VM4();
        BAR();
        RD_Q(0, 0, arA); SB();
        PRIO1(); LG(4); MF4(3,0,arB); MF4(3,1,arB); MF4(3,2,arB); MF4(3,3,arB); PRIO0();
        BAR();
    }
    asm volatile("s_waitcnt vmcnt(0) lgkmcnt(0)" ::: "memory");

    // epilogue
    const float s = *scale_p;
    const int row0 = bm * 256 + wr * 128;
    const int col0 = bn * 256 + wc * 64;
    #pragma unroll
    for (int mf = 0; mf < 8; ++mf) {
        #pragma unroll
        for (int nf = 0; nf < 4; ++nf) {
            int row = row0 + mf * 16 + l4 * 4;
            int col = col0 + nf * 16 + l15;
            float* cp = C + (size_t)row * N_DIM + col;
            #pragma unroll
            for (int r = 0; r < 4; ++r)
                cp[(size_t)r * N_DIM] = s * acc[mf][nf][r];
        }
    }
#undef STAGEA
#undef STAGEB
#undef RD_Q
#undef RD_B
#undef MF4
#undef BAR
#undef SB
#undef LG
#undef VM4
#undef PRIO1
#undef PRIO0
}

// ---------------------------------------------------------------------------
__global__ void naive_kernel(const float* __restrict__ x, const void* __restrict__ w,
                             const int* __restrict__ flag, const float* __restrict__ scale_p,
                             float* __restrict__ out) {
    int n = blockIdx.x * 256 + threadIdx.x;
    int m = blockIdx.y;
    int kind = *flag;
    const float* xr = x + (size_t)m * K_DIM;
    float acc = 0.f;
    for (int k = 0; k < K_DIM; ++k) {
        float xv = xr[k];
        if (k >= N_EXC) xv = -4.0f * xv;
        size_t gi = (size_t)k * N_DIM + n;
        float wv;
        if (kind == 0)      wv = (float)((const int*)w)[gi];
        else if (kind == 1) wv = (float)((const unsigned char*)w)[gi];
        else                wv = ((const float*)w)[gi];
        acc += xv * wv;
    }
    out[(size_t)m * N_DIM + n] = acc * (*scale_p);
}

extern "C" void kernel_launch(void* const* d_in, const int* in_sizes, int n_in,
                              void* d_out, int out_size, void* d_ws, size_t ws_size,
                              hipStream_t stream) {
    const float* x       = (const float*)d_in[0];
    const void*  w       = d_in[1];
    const float* scale_p = (const float*)d_in[2];
    float* out = (float*)d_out;

    const size_t xb_bytes = (size_t)M_DIM * K_DIM * 2;
    const size_t wb_bytes = (size_t)N_DIM * K_DIM * 2;
    const size_t need = xb_bytes + wb_bytes + 256;

    if (ws_size >= need) {
        unsigned short* xb  = (unsigned short*)d_ws;
        unsigned short* wbt = (unsigned short*)((char*)d_ws + xb_bytes);
        int* flag = (int*)((char*)d_ws + xb_bytes + wb_bytes);
        detect_kind<<<1, 256, 0, stream>>>((const unsigned char*)w, flag);
        conv_x_kernel<<<(M_DIM * K_DIM) / (256 * 8), 256, 0, stream>>>(x, xb);
        conv_w_kernel<<<(K_DIM / 64) * (N_DIM / 64), 256, 0, stream>>>(w, flag, wbt);
        gemm8_kernel<<<(M_DIM / 256) * (N_DIM / 256), 512, 0, stream>>>(xb, wbt, out, scale_p);
    } else if (ws_size >= 4) {
        int* flag = (int*)d_ws;
        detect_kind<<<1, 256, 0, stream>>>((const unsigned char*)w, flag);
        dim3 g(N_DIM / 256, M_DIM);
        naive_kernel<<<g, 256, 0, stream>>>(x, w, flag, scale_p, out);
    }
}